// Round 10
// baseline (145.954 us; speedup 1.0000x reference)
//
#include <hip/hip_runtime.h>

// Decoder: N=4096 LSTM seqs (K=16 x B=256), H=64, T=50, GMM head (GC=16, PD=2).
// Round 10: latency-hiding recurrence.
//  k0: pack weights (Wih/Wh0/Wc0 hi/lo, Whh RNE, proj RNE) into ws.
//  k1: recurrence ONLY. 1024 blocks x 4 waves x 4 SAMPLES (sample s on A-row 4s)
//      -> each lane owns exactly 1 cell element (sample g, unit 16w+c);
//      4 blocks/CU = 4 independent chains per SIMD (latency hiding).
//      16 MFMA/step/wave, raw s_barrier + lgkmcnt-only (no vmcnt drain).
//  k2: proj + GMM, parallel (1024 blocks), single-plane RNE proj weights.

#define T_ 50
typedef __attribute__((ext_vector_type(8))) short short8;
typedef __attribute__((ext_vector_type(4))) float f32x4;
#define MFMA(a,b,c) __builtin_amdgcn_mfma_f32_16x16x32_bf16(a,b,c,0,0,0)

// ws layout (bytes): Hout ushort[50][4096][64] = 26,214,400 ; WF after
#define HOUT_B 0u
#define WF_B   26214400u
// WF slot bases (short8 slots; addr = (BASE+rel)*64 + lane)
#define WIH_S 0
#define WH0_S 320
#define WC0_S 400
#define WHH_S 480
#define PRJ_S 512

#define HFS 76   // h plane stride (ushorts): bank-spread for b128 reads

__device__ __forceinline__ float sigf(float x)  { return 1.0f / (1.0f + __expf(-x)); }
__device__ __forceinline__ float tanh_(float x) { return 1.0f - 2.0f / (__expf(2.0f * x) + 1.0f); }

__device__ __forceinline__ void splitf(float f, unsigned short& hi, unsigned short& lo) {
    unsigned b = __float_as_uint(f);
    hi = (unsigned short)(b >> 16);
    float fh = __uint_as_float(b & 0xffff0000u);
    lo = (unsigned short)(__float_as_uint(f - fh) >> 16);
}
__device__ __forceinline__ void pack8(const float* p, short8& hi, short8& lo) {
    #pragma unroll
    for (int e = 0; e < 8; ++e) {
        unsigned short h, l;
        splitf(p[e], h, l);
        hi[e] = (short)h; lo[e] = (short)l;
    }
}
__device__ __forceinline__ unsigned short bf16rn(float f) {
    unsigned b = __float_as_uint(f);
    unsigned r = b + 0x7fffu + ((b >> 16) & 1u);
    return (unsigned short)(r >> 16);
}
__device__ __forceinline__ void pack8rn(const float* p, short8& hi) {
    #pragma unroll
    for (int e = 0; e < 8; ++e) hi[e] = (short)bf16rn(p[e]);
}

// ---------------- k0: weight packing ----------------
__global__ void pack_kernel(const float* __restrict__ Wih, const float* __restrict__ Whh,
                            const float* __restrict__ Wh0, const float* __restrict__ Wc0,
                            const float* __restrict__ Wpi, const float* __restrict__ Wmu,
                            const float* __restrict__ Wls, const float* __restrict__ Wcorr,
                            short8* __restrict__ WF)
{
    int id = blockIdx.x * 256 + threadIdx.x;
    if (id >= 18176) return;
    if (id < 10240) {                               // Wih hi/lo
        int ks = id >> 10, rem = id & 1023;
        int q = rem >> 8, w = (rem >> 6) & 3, l = rem & 63;
        int g = l >> 4, c = l & 15;
        const float* src = Wih + (q*64 + w*16 + c)*322 + ks*32 + g*8;
        short8 hi, lo; pack8(src, hi, lo);
        WF[(WIH_S + ((ks*4 + q)*2 + 0)*4 + w)*64 + l] = hi;
        WF[(WIH_S + ((ks*4 + q)*2 + 1)*4 + w)*64 + l] = lo;
    } else if (id < 12800) {                        // Wh0 hi/lo
        int t2 = id - 10240;
        int ks = t2 >> 8, w = (t2 >> 6) & 3, l = t2 & 63;
        int g = l >> 4, c = l & 15;
        const float* src = Wh0 + (w*16 + c)*320 + ks*32 + g*8;
        short8 hi, lo; pack8(src, hi, lo);
        WF[(WH0_S + (ks*2 + 0)*4 + w)*64 + l] = hi;
        WF[(WH0_S + (ks*2 + 1)*4 + w)*64 + l] = lo;
    } else if (id < 15360) {                        // Wc0 hi/lo
        int t2 = id - 12800;
        int ks = t2 >> 8, w = (t2 >> 6) & 3, l = t2 & 63;
        int g = l >> 4, c = l & 15;
        const float* src = Wc0 + (w*16 + c)*320 + ks*32 + g*8;
        short8 hi, lo; pack8(src, hi, lo);
        WF[(WC0_S + (ks*2 + 0)*4 + w)*64 + l] = hi;
        WF[(WC0_S + (ks*2 + 1)*4 + w)*64 + l] = lo;
    } else if (id < 17408) {                        // Whh RNE
        int t3 = id - 15360;
        int slot = t3 >> 6, l = t3 & 63;
        int g = l >> 4, c = l & 15;
        int tile = slot >> 1, ks = slot & 1;
        int q = tile >> 2, wt = tile & 3;
        short8 hi; pack8rn(Whh + (q*64 + 16*wt + c)*64 + ks*32 + g*8, hi);
        WF[(WHH_S + slot)*64 + l] = hi;
    } else {                                        // proj RNE (12 slots)
        int t4 = id - 17408;
        int r = t4 >> 6, l = t4 & 63;
        int g = l >> 4, c = l & 15;
        int pt = r >> 1, ks = r & 1;
        int r3 = pt*16 + c;
        const float* p;
        if      (r3 < 16) p = Wpi   + r3*64;
        else if (r3 < 48) p = Wmu   + (r3-16)*64;
        else if (r3 < 80) p = Wls   + (r3-48)*64;
        else              p = Wcorr + (r3-80)*64;
        short8 hi; pack8rn(p + ks*32 + g*8, hi);
        WF[(PRJ_S + r)*64 + l] = hi;
    }
}

// ---------------- k1: LSTM recurrence only ----------------
__launch_bounds__(256, 4)
__global__ void lstm_kernel(
    const float* __restrict__ x,        const float* __restrict__ z,
    const float* __restrict__ inp_seqs, const float* __restrict__ pred_seqs,
    const float* __restrict__ Wih,      const float* __restrict__ bh0,
    const float* __restrict__ bc0,      const float* __restrict__ bih,
    const float* __restrict__ bhh,
    unsigned short* __restrict__ Hout,  const short8* __restrict__ WF)
{
    __shared__ __align__(16) float ZXL[16*324];            // prologue A (rows 4s)
    __shared__ __align__(16) float DQ[T_*8];               // d inputs
    __shared__ __align__(16) unsigned short HP[4][16*HFS]; // h0hi,h0lo,h1hi,h1lo

    const int j = threadIdx.x;
    const int w = j >> 6, l = j & 63, g = l >> 4, c = l & 15;
    const int U = 16*w + c;
    const int blk = blockIdx.x, nb = blk*4;

    // ---- zero ZXL + HP
    for (int e = j; e < 16*324; e += 256) ZXL[e] = 0.0f;
    for (int e = j; e < 4*16*HFS; e += 256) (&HP[0][0])[e] = 0;
    __syncthreads();
    // ---- fill ZXL rows 4s; DQ (t=0 present, else FUT[t-1])
    for (int e = j; e < 4*320; e += 256) {
        int s = e / 320, k = e - s*320;
        int n = nb + s, b = n & 255;
        ZXL[(4*s)*324 + k] = (k < 64) ? z[n*64 + k] : x[b*256 + (k - 64)];
    }
    for (int e = j; e < T_*8; e += 256) {
        int t = e >> 3, rem = e & 7, s = rem >> 1, comp = rem & 1;
        int b = (nb + s) & 255;
        DQ[e] = (t == 0) ? inp_seqs[b*192 + 188 + comp]
                         : pred_seqs[b*1200 + (t-1)*24 + 20 + comp];
    }
    __syncthreads();

    // ---- prologue GEMM: wave w -> gc tiles q (units 16w..16w+15), h0, c0
    f32x4 gcA[4], h0a, c0a;
    #pragma unroll
    for (int q = 0; q < 4; ++q) {
        int ga = q*64 + U;
        float b_ = bih[ga] + bhh[ga];
        gcA[q] = (f32x4){b_, b_, b_, b_};
    }
    {
        float bh_ = bh0[U], bc_ = bc0[U];
        h0a = (f32x4){bh_, bh_, bh_, bh_};
        c0a = (f32x4){bc_, bc_, bc_, bc_};
    }
    for (int ks = 0; ks < 10; ++ks) {
        short8 ah, al;
        pack8(&ZXL[c*324 + ks*32 + g*8], ah, al);
        #pragma unroll
        for (int q = 0; q < 4; ++q) {
            short8 Bh = WF[(WIH_S + ((ks*4 + q)*2 + 0)*4 + w)*64 + l];
            short8 Bl = WF[(WIH_S + ((ks*4 + q)*2 + 1)*4 + w)*64 + l];
            gcA[q] = MFMA(ah, Bh, gcA[q]);
            gcA[q] = MFMA(ah, Bl, gcA[q]);
            gcA[q] = MFMA(al, Bh, gcA[q]);
        }
        {
            short8 Bh = WF[(WH0_S + (ks*2 + 0)*4 + w)*64 + l];
            short8 Bl = WF[(WH0_S + (ks*2 + 1)*4 + w)*64 + l];
            h0a = MFMA(ah, Bh, h0a); h0a = MFMA(ah, Bl, h0a); h0a = MFMA(al, Bh, h0a);
        }
        {
            short8 Bh = WF[(WC0_S + (ks*2 + 0)*4 + w)*64 + l];
            short8 Bl = WF[(WC0_S + (ks*2 + 1)*4 + w)*64 + l];
            c0a = MFMA(ah, Bh, c0a); c0a = MFMA(ah, Bl, c0a); c0a = MFMA(al, Bh, c0a);
        }
    }
    // this lane's element: (sample g, unit U) — D row 4g, reg 0
    float gcs[4];
    #pragma unroll
    for (int q = 0; q < 4; ++q) gcs[q] = gcA[q][0];
    float cst = c0a[0];
    {
        unsigned short hh, ll; splitf(h0a[0], hh, ll);
        HP[0][(4*g)*HFS + U] = hh;
        HP[1][(4*g)*HFS + U] = ll;
    }
    // d-weights + Whh RNE frags
    float wd0[4], wd1[4];
    #pragma unroll
    for (int q = 0; q < 4; ++q) {
        int ga = q*64 + U;
        wd0[q] = Wih[ga*322 + 320];
        wd1[q] = Wih[ga*322 + 321];
    }
    short8 WB[4][2];
    #pragma unroll
    for (int q = 0; q < 4; ++q)
        #pragma unroll
        for (int ks = 0; ks < 2; ++ks)
            WB[q][ks] = WF[(WHH_S + (q*4 + w)*2 + ks)*64 + l];

    asm volatile("s_waitcnt lgkmcnt(0)" ::: "memory");
    __builtin_amdgcn_s_barrier();
    asm volatile("" ::: "memory");

    // ---- main loop: raw barrier, lgkm-only waits, vmcnt never drained
    for (int t = 0; t < T_; ++t) {
        const unsigned short* Hh = HP[2*(t & 1)];
        const unsigned short* Hl = HP[2*(t & 1) + 1];
        unsigned short* Nh = HP[2*((t + 1) & 1)];
        unsigned short* Nl = HP[2*((t + 1) & 1) + 1];

        short8 ah0 = *reinterpret_cast<const short8*>(Hh + c*HFS +      g*8);
        short8 al0 = *reinterpret_cast<const short8*>(Hl + c*HFS +      g*8);
        short8 ah1 = *reinterpret_cast<const short8*>(Hh + c*HFS + 32 + g*8);
        short8 al1 = *reinterpret_cast<const short8*>(Hl + c*HFS + 32 + g*8);
        float dx = DQ[t*8 + g*2], dy = DQ[t*8 + g*2 + 1];

        f32x4 aq[4];
        #pragma unroll
        for (int q = 0; q < 4; ++q) {
            f32x4 a;
            a[0] = gcs[q] + dx*wd0[q] + dy*wd1[q];
            a[1] = 0.0f; a[2] = 0.0f; a[3] = 0.0f;
            a = MFMA(ah0, WB[q][0], a);
            a = MFMA(al0, WB[q][0], a);
            a = MFMA(ah1, WB[q][1], a);
            a = MFMA(al1, WB[q][1], a);
            aq[q] = a;
        }
        float cc = sigf(aq[1][0])*cst + sigf(aq[0][0])*tanh_(aq[2][0]);
        cst = cc;
        float hv = sigf(aq[3][0])*tanh_(cc);
        unsigned short hh, ll; splitf(hv, hh, ll);
        Nh[(4*g)*HFS + U] = hh;
        Nl[(4*g)*HFS + U] = ll;
        Hout[(size_t)(t*4096 + nb + g)*64 + U] = bf16rn(hv);

        asm volatile("s_waitcnt lgkmcnt(0)" ::: "memory");
        __builtin_amdgcn_s_barrier();
        asm volatile("" ::: "memory");
    }
}

// ---------------- k2: proj + GMM ----------------
__launch_bounds__(256, 3)
__global__ void head_kernel(const float* __restrict__ pred_seqs,
                            const float* __restrict__ bpi, const float* __restrict__ bmu,
                            const float* __restrict__ bls, const float* __restrict__ bcorr,
                            const unsigned short* __restrict__ Hin,
                            const short8* __restrict__ WF,
                            float* __restrict__ out)
{
    __shared__ __align__(16) float PL[4][1600];   // per-wave 16 x 100
    const int j = threadIdx.x;
    const int w = j >> 6;
    const int l = j & 63;
    const int g = l >> 4;
    const int c = l & 15;
    const int blk = blockIdx.x;
    const int set = blk >> 2, chunk = blk & 3;
    const int t0 = (chunk*25) >> 1, t1 = ((chunk+1)*25) >> 1;

    float bias[6];
    #pragma unroll
    for (int pt = 0; pt < 6; ++pt) {
        int r3 = pt*16 + c;
        bias[pt] = (r3 < 16) ? bpi[r3] : (r3 < 48) ? bmu[r3-16]
                 : (r3 < 80) ? bls[r3-48] : bcorr[r3-80];
    }

    const int s = l >> 2, q4 = l & 3;
    const int n_s = set*16 + s, b_s = n_s & 255;
    float* PLw = &PL[w][0];
    float sum_local = 0.0f;

    for (int t = t0 + w; t < t1; t += 4) {
        const unsigned short* hp = Hin + (size_t)(t*4096 + set*16 + c)*64;
        short8 ah0 = *reinterpret_cast<const short8*>(hp + g*8);
        short8 ah1 = *reinterpret_cast<const short8*>(hp + 32 + g*8);
        #pragma unroll
        for (int pt = 0; pt < 6; ++pt) {
            short8 B0 = WF[(PRJ_S + pt*2 + 0)*64 + l];
            short8 B1 = WF[(PRJ_S + pt*2 + 1)*64 + l];
            f32x4 p = (f32x4){bias[pt], bias[pt], bias[pt], bias[pt]};
            p = MFMA(ah0, B0, p);
            p = MFMA(ah1, B1, p);
            #pragma unroll
            for (int r = 0; r < 4; ++r) PLw[(4*g + r)*100 + pt*16 + c] = p[r];
        }
        asm volatile("s_waitcnt lgkmcnt(0)" ::: "memory");
        __builtin_amdgcn_sched_barrier(0);

        float2 tv = *reinterpret_cast<const float2*>(pred_seqs + b_s*1200 + t*24 + 20);
        float a[4], m = -1e30f, Ppi = 0.0f;
        #pragma unroll
        for (int i = 0; i < 4; ++i) {
            int cq = q4*4 + i;
            float pi = PLw[s*100 + cq];
            float2 mu = *reinterpret_cast<const float2*>(PLw + s*100 + 16 + 2*cq);
            float2 ls = *reinterpret_cast<const float2*>(PLw + s*100 + 48 + 2*cq);
            float co = PLw[s*100 + 80 + cq];
            float l0 = fminf(fmaxf(ls.x, -10.0f), 10.0f);
            float l1 = fminf(fmaxf(ls.y, -10.0f), 10.0f);
            float z0 = (tv.x - mu.x) * __expf(-l0);
            float z1 = (tv.y - mu.y) * __expf(-l1);
            float ct = tanh_(co);
            float omr = 1.0f - ct*ct;
            float quad = z0*z0 + z1*z1 - 2.0f*ct*z0*z1;
            float comp = -1.8378770664093453f - (l0 + l1) - 0.5f*__logf(omr) - 0.5f*quad/omr;
            a[i] = pi + comp;
            m = fmaxf(m, a[i]);
            Ppi += __expf(pi);
        }
        m = fmaxf(m, __shfl_xor(m, 1));
        m = fmaxf(m, __shfl_xor(m, 2));
        float E = __expf(a[0]-m) + __expf(a[1]-m) + __expf(a[2]-m) + __expf(a[3]-m);
        E   += __shfl_xor(E, 1);   E   += __shfl_xor(E, 2);
        Ppi += __shfl_xor(Ppi, 1); Ppi += __shfl_xor(Ppi, 2);
        float logp = m + __logf(E) - __logf(Ppi);
        sum_local += fminf(logp, 50.0f);
    }
    if (q4 == 0) atomicAdd(out + n_s, sum_local);
}

extern "C" void kernel_launch(void* const* d_in, const int* in_sizes, int n_in,
                              void* d_out, int out_size, void* d_ws, size_t ws_size,
                              hipStream_t stream) {
    const float* x     = (const float*)d_in[0];
    const float* z     = (const float*)d_in[1];
    const float* iseq  = (const float*)d_in[2];
    const float* pseq  = (const float*)d_in[3];
    const float* Wh0   = (const float*)d_in[4];
    const float* bh0   = (const float*)d_in[5];
    const float* Wc0   = (const float*)d_in[6];
    const float* bc0   = (const float*)d_in[7];
    const float* Wih   = (const float*)d_in[8];
    const float* Whh   = (const float*)d_in[9];
    const float* bih   = (const float*)d_in[10];
    const float* bhh   = (const float*)d_in[11];
    const float* Wpi   = (const float*)d_in[12];
    const float* bpi   = (const float*)d_in[13];
    const float* Wmu   = (const float*)d_in[14];
    const float* bmu   = (const float*)d_in[15];
    const float* Wls   = (const float*)d_in[16];
    const float* bls   = (const float*)d_in[17];
    const float* Wcorr = (const float*)d_in[18];
    const float* bcorr = (const float*)d_in[19];
    float* out = (float*)d_out;

    char* ws = (char*)d_ws;
    unsigned short* Hout = (unsigned short*)(ws + HOUT_B);
    short8* WF = (short8*)(ws + WF_B);

    pack_kernel<<<71, 256, 0, stream>>>(Wih, Whh, Wh0, Wc0, Wpi, Wmu, Wls, Wcorr, WF);
    hipMemsetAsync(d_out, 0, 4096 * sizeof(float), stream);
    lstm_kernel<<<1024, 256, 0, stream>>>(x, z, iseq, pseq, Wih, bh0, bc0, bih, bhh,
                                          Hout, (const short8*)WF);
    head_kernel<<<1024, 256, 0, stream>>>(pseq, bpi, bmu, bls, bcorr,
                                          (const unsigned short*)Hout,
                                          (const short8*)WF, out);
}

// Round 11
// 103.986 us; speedup vs baseline: 1.4036x; 1.4036x over previous
//
#include <hip/hip_runtime.h>

// Decoder: N=4096 LSTM seqs (K=16 x B=256), H=64, T=50, GMM head (GC=16, PD=2).
// Round 11: two-chains-per-SIMD recurrence.
//  k0: pack weights (Wih/Wh0/Wc0 hi/lo, Whh RNE, proj RNE) into ws.
//  k1: recurrence ONLY. 512 blocks x 4 waves x 8 samples, samples on EVEN
//      A-rows (sample s -> row 2s) so every lane owns exactly 2 cell elements
//      (samples 2g,2g+1, unit 16w+c) -> trans work spread over all 64 lanes.
//      16 MFMA/step/wave (2-pass RNE Whh), raw s_barrier + lgkm-only waits
//      (in-loop h->HBM stores never drain vmcnt). 2 blocks/CU = 2 independent
//      chains per SIMD to hide the ~800-cycle dependency stall.
//  k2: proj + GMM, parallel (1024 blocks), single-plane RNE proj weights.

#define T_ 50
typedef __attribute__((ext_vector_type(8))) short short8;
typedef __attribute__((ext_vector_type(4))) float f32x4;
#define MFMA(a,b,c) __builtin_amdgcn_mfma_f32_16x16x32_bf16(a,b,c,0,0,0)

// ws layout (bytes): Hout ushort[50][4096][64] = 26,214,400 ; WF after
#define HOUT_B 0u
#define WF_B   26214400u
// WF slot bases (short8 slots; addr = (BASE+rel)*64 + lane)
#define WIH_S 0
#define WH0_S 320
#define WC0_S 400
#define WHH_S 480
#define PRJ_S 512

#define HFS 76   // h plane stride (ushorts)

__device__ __forceinline__ float sigf(float x)  { return 1.0f / (1.0f + __expf(-x)); }
__device__ __forceinline__ float tanh_(float x) { return 1.0f - 2.0f / (__expf(2.0f * x) + 1.0f); }

__device__ __forceinline__ void splitf(float f, unsigned short& hi, unsigned short& lo) {
    unsigned b = __float_as_uint(f);
    hi = (unsigned short)(b >> 16);
    float fh = __uint_as_float(b & 0xffff0000u);
    lo = (unsigned short)(__float_as_uint(f - fh) >> 16);
}
__device__ __forceinline__ void pack8(const float* p, short8& hi, short8& lo) {
    #pragma unroll
    for (int e = 0; e < 8; ++e) {
        unsigned short h, l;
        splitf(p[e], h, l);
        hi[e] = (short)h; lo[e] = (short)l;
    }
}
__device__ __forceinline__ unsigned short bf16rn(float f) {
    unsigned b = __float_as_uint(f);
    unsigned r = b + 0x7fffu + ((b >> 16) & 1u);
    return (unsigned short)(r >> 16);
}
__device__ __forceinline__ void pack8rn(const float* p, short8& hi) {
    #pragma unroll
    for (int e = 0; e < 8; ++e) hi[e] = (short)bf16rn(p[e]);
}

// ---------------- k0: weight packing ----------------
__global__ void pack_kernel(const float* __restrict__ Wih, const float* __restrict__ Whh,
                            const float* __restrict__ Wh0, const float* __restrict__ Wc0,
                            const float* __restrict__ Wpi, const float* __restrict__ Wmu,
                            const float* __restrict__ Wls, const float* __restrict__ Wcorr,
                            short8* __restrict__ WF)
{
    int id = blockIdx.x * 256 + threadIdx.x;
    if (id >= 18176) return;
    if (id < 10240) {                               // Wih hi/lo
        int ks = id >> 10, rem = id & 1023;
        int q = rem >> 8, w = (rem >> 6) & 3, l = rem & 63;
        int g = l >> 4, c = l & 15;
        const float* src = Wih + (q*64 + w*16 + c)*322 + ks*32 + g*8;
        short8 hi, lo; pack8(src, hi, lo);
        WF[(WIH_S + ((ks*4 + q)*2 + 0)*4 + w)*64 + l] = hi;
        WF[(WIH_S + ((ks*4 + q)*2 + 1)*4 + w)*64 + l] = lo;
    } else if (id < 12800) {                        // Wh0 hi/lo
        int t2 = id - 10240;
        int ks = t2 >> 8, w = (t2 >> 6) & 3, l = t2 & 63;
        int g = l >> 4, c = l & 15;
        const float* src = Wh0 + (w*16 + c)*320 + ks*32 + g*8;
        short8 hi, lo; pack8(src, hi, lo);
        WF[(WH0_S + (ks*2 + 0)*4 + w)*64 + l] = hi;
        WF[(WH0_S + (ks*2 + 1)*4 + w)*64 + l] = lo;
    } else if (id < 15360) {                        // Wc0 hi/lo
        int t2 = id - 12800;
        int ks = t2 >> 8, w = (t2 >> 6) & 3, l = t2 & 63;
        int g = l >> 4, c = l & 15;
        const float* src = Wc0 + (w*16 + c)*320 + ks*32 + g*8;
        short8 hi, lo; pack8(src, hi, lo);
        WF[(WC0_S + (ks*2 + 0)*4 + w)*64 + l] = hi;
        WF[(WC0_S + (ks*2 + 1)*4 + w)*64 + l] = lo;
    } else if (id < 17408) {                        // Whh RNE
        int t3 = id - 15360;
        int slot = t3 >> 6, l = t3 & 63;
        int g = l >> 4, c = l & 15;
        int tile = slot >> 1, ks = slot & 1;
        int q = tile >> 2, wt = tile & 3;
        short8 hi; pack8rn(Whh + (q*64 + 16*wt + c)*64 + ks*32 + g*8, hi);
        WF[(WHH_S + slot)*64 + l] = hi;
    } else {                                        // proj RNE (12 slots)
        int t4 = id - 17408;
        int r = t4 >> 6, l = t4 & 63;
        int g = l >> 4, c = l & 15;
        int pt = r >> 1, ks = r & 1;
        int r3 = pt*16 + c;
        const float* p;
        if      (r3 < 16) p = Wpi   + r3*64;
        else if (r3 < 48) p = Wmu   + (r3-16)*64;
        else if (r3 < 80) p = Wls   + (r3-48)*64;
        else              p = Wcorr + (r3-80)*64;
        short8 hi; pack8rn(p + ks*32 + g*8, hi);
        WF[(PRJ_S + r)*64 + l] = hi;
    }
}

// ---------------- k1: LSTM recurrence only ----------------
__launch_bounds__(256, 2)
__global__ void lstm_kernel(
    const float* __restrict__ x,        const float* __restrict__ z,
    const float* __restrict__ inp_seqs, const float* __restrict__ pred_seqs,
    const float* __restrict__ Wih,      const float* __restrict__ bh0,
    const float* __restrict__ bc0,      const float* __restrict__ bih,
    const float* __restrict__ bhh,
    unsigned short* __restrict__ Hout,  const short8* __restrict__ WF)
{
    __shared__ __align__(16) float ZXL[16*324];            // rows 2s filled
    __shared__ __align__(16) float DQ[T_*16];              // d inputs (8 samples x 2)
    __shared__ __align__(16) unsigned short HP[4][16*HFS]; // h0hi,h0lo,h1hi,h1lo

    const int j = threadIdx.x;
    const int w = j >> 6, l = j & 63, g = l >> 4, c = l & 15;
    const int U = 16*w + c;
    const int blk = blockIdx.x, nb = blk*8;

    // ---- zero ZXL + HP
    for (int e = j; e < 16*324; e += 256) ZXL[e] = 0.0f;
    for (int e = j; e < 4*16*HFS; e += 256) (&HP[0][0])[e] = 0;
    __syncthreads();
    // ---- fill ZXL even rows; DQ (t=0 present, else FUT[t-1])
    for (int e = j; e < 8*320; e += 256) {
        int s = e / 320, k = e - s*320;
        int n = nb + s, b = n & 255;
        ZXL[(2*s)*324 + k] = (k < 64) ? z[n*64 + k] : x[b*256 + (k - 64)];
    }
    for (int e = j; e < T_*16; e += 256) {
        int t = e >> 4, rem = e & 15, s = rem >> 1, comp = rem & 1;
        int b = (nb + s) & 255;
        DQ[e] = (t == 0) ? inp_seqs[b*192 + 188 + comp]
                         : pred_seqs[b*1200 + (t-1)*24 + 20 + comp];
    }
    __syncthreads();

    // ---- prologue GEMM: wave w -> 4 gc tiles (units 16w..16w+15), h0, c0
    f32x4 gcA[4], h0a, c0a;
    #pragma unroll
    for (int q = 0; q < 4; ++q) {
        int ga = q*64 + U;
        float b_ = bih[ga] + bhh[ga];
        gcA[q] = (f32x4){b_, 0.0f, b_, 0.0f};
    }
    {
        float bh_ = bh0[U], bc_ = bc0[U];
        h0a = (f32x4){bh_, 0.0f, bh_, 0.0f};
        c0a = (f32x4){bc_, 0.0f, bc_, 0.0f};
    }
    for (int ks = 0; ks < 10; ++ks) {
        short8 ah, al;
        pack8(&ZXL[c*324 + ks*32 + g*8], ah, al);
        #pragma unroll
        for (int q = 0; q < 4; ++q) {
            short8 Bh = WF[(WIH_S + ((ks*4 + q)*2 + 0)*4 + w)*64 + l];
            short8 Bl = WF[(WIH_S + ((ks*4 + q)*2 + 1)*4 + w)*64 + l];
            gcA[q] = MFMA(ah, Bh, gcA[q]);
            gcA[q] = MFMA(ah, Bl, gcA[q]);
            gcA[q] = MFMA(al, Bh, gcA[q]);
        }
        {
            short8 Bh = WF[(WH0_S + (ks*2 + 0)*4 + w)*64 + l];
            short8 Bl = WF[(WH0_S + (ks*2 + 1)*4 + w)*64 + l];
            h0a = MFMA(ah, Bh, h0a); h0a = MFMA(ah, Bl, h0a); h0a = MFMA(al, Bh, h0a);
        }
        {
            short8 Bh = WF[(WC0_S + (ks*2 + 0)*4 + w)*64 + l];
            short8 Bl = WF[(WC0_S + (ks*2 + 1)*4 + w)*64 + l];
            c0a = MFMA(ah, Bh, c0a); c0a = MFMA(ah, Bl, c0a); c0a = MFMA(al, Bh, c0a);
        }
    }
    // this lane's cell elements: D rows 4g (r=0) and 4g+2 (r=2)
    //   -> samples 2g, 2g+1 at unit U
    float gcs0[4], gcs1[4];
    #pragma unroll
    for (int q = 0; q < 4; ++q) { gcs0[q] = gcA[q][0]; gcs1[q] = gcA[q][2]; }
    float cst0 = c0a[0], cst1 = c0a[2];
    {
        unsigned short hh, ll;
        splitf(h0a[0], hh, ll);
        HP[0][(4*g)*HFS + U] = hh;     HP[1][(4*g)*HFS + U] = ll;
        splitf(h0a[2], hh, ll);
        HP[0][(4*g + 2)*HFS + U] = hh; HP[1][(4*g + 2)*HFS + U] = ll;
    }
    // d-weights + Whh RNE frags
    float wd0[4], wd1[4];
    #pragma unroll
    for (int q = 0; q < 4; ++q) {
        int ga = q*64 + U;
        wd0[q] = Wih[ga*322 + 320];
        wd1[q] = Wih[ga*322 + 321];
    }
    short8 WB[4][2];
    #pragma unroll
    for (int q = 0; q < 4; ++q)
        #pragma unroll
        for (int ks = 0; ks < 2; ++ks)
            WB[q][ks] = WF[(WHH_S + (q*4 + w)*2 + ks)*64 + l];

    asm volatile("s_waitcnt lgkmcnt(0)" ::: "memory");
    __builtin_amdgcn_s_barrier();
    asm volatile("" ::: "memory");

    // ---- main loop: raw barrier, lgkm-only waits, vmcnt never drained
    for (int t = 0; t < T_; ++t) {
        const unsigned short* Hh = HP[2*(t & 1)];
        const unsigned short* Hl = HP[2*(t & 1) + 1];
        unsigned short* Nh = HP[2*((t + 1) & 1)];
        unsigned short* Nl = HP[2*((t + 1) & 1) + 1];

        short8 ah0 = *reinterpret_cast<const short8*>(Hh + c*HFS +      g*8);
        short8 al0 = *reinterpret_cast<const short8*>(Hl + c*HFS +      g*8);
        short8 ah1 = *reinterpret_cast<const short8*>(Hh + c*HFS + 32 + g*8);
        short8 al1 = *reinterpret_cast<const short8*>(Hl + c*HFS + 32 + g*8);
        f32x4 dv = *reinterpret_cast<const f32x4*>(DQ + t*16 + 4*g);  // dx0,dy0,dx1,dy1

        f32x4 aq[4];
        #pragma unroll
        for (int q = 0; q < 4; ++q) {
            f32x4 a;
            a[0] = gcs0[q] + dv[0]*wd0[q] + dv[1]*wd1[q];
            a[1] = 0.0f;
            a[2] = gcs1[q] + dv[2]*wd0[q] + dv[3]*wd1[q];
            a[3] = 0.0f;
            a = MFMA(ah0, WB[q][0], a);
            a = MFMA(al0, WB[q][0], a);
            a = MFMA(ah1, WB[q][1], a);
            a = MFMA(al1, WB[q][1], a);
            aq[q] = a;
        }
        float cc0 = sigf(aq[1][0])*cst0 + sigf(aq[0][0])*tanh_(aq[2][0]);
        float cc1 = sigf(aq[1][2])*cst1 + sigf(aq[0][2])*tanh_(aq[2][2]);
        cst0 = cc0; cst1 = cc1;
        float hv0 = sigf(aq[3][0])*tanh_(cc0);
        float hv1 = sigf(aq[3][2])*tanh_(cc1);
        unsigned short hh, ll;
        splitf(hv0, hh, ll);
        Nh[(4*g)*HFS + U] = hh;     Nl[(4*g)*HFS + U] = ll;
        splitf(hv1, hh, ll);
        Nh[(4*g + 2)*HFS + U] = hh; Nl[(4*g + 2)*HFS + U] = ll;
        Hout[(size_t)(t*4096 + nb + 2*g)*64 + U]     = bf16rn(hv0);
        Hout[(size_t)(t*4096 + nb + 2*g + 1)*64 + U] = bf16rn(hv1);

        asm volatile("s_waitcnt lgkmcnt(0)" ::: "memory");
        __builtin_amdgcn_s_barrier();
        asm volatile("" ::: "memory");
    }
}

// ---------------- k2: proj + GMM ----------------
__launch_bounds__(256, 3)
__global__ void head_kernel(const float* __restrict__ pred_seqs,
                            const float* __restrict__ bpi, const float* __restrict__ bmu,
                            const float* __restrict__ bls, const float* __restrict__ bcorr,
                            const unsigned short* __restrict__ Hin,
                            const short8* __restrict__ WF,
                            float* __restrict__ out)
{
    __shared__ __align__(16) float PL[4][1600];   // per-wave 16 x 100
    const int j = threadIdx.x;
    const int w = j >> 6;
    const int l = j & 63;
    const int g = l >> 4;
    const int c = l & 15;
    const int blk = blockIdx.x;
    const int set = blk >> 2, chunk = blk & 3;
    const int t0 = (chunk*25) >> 1, t1 = ((chunk+1)*25) >> 1;

    float bias[6];
    #pragma unroll
    for (int pt = 0; pt < 6; ++pt) {
        int r3 = pt*16 + c;
        bias[pt] = (r3 < 16) ? bpi[r3] : (r3 < 48) ? bmu[r3-16]
                 : (r3 < 80) ? bls[r3-48] : bcorr[r3-80];
    }

    const int s = l >> 2, q4 = l & 3;
    const int n_s = set*16 + s, b_s = n_s & 255;
    float* PLw = &PL[w][0];
    float sum_local = 0.0f;

    for (int t = t0 + w; t < t1; t += 4) {
        const unsigned short* hp = Hin + (size_t)(t*4096 + set*16 + c)*64;
        short8 ah0 = *reinterpret_cast<const short8*>(hp + g*8);
        short8 ah1 = *reinterpret_cast<const short8*>(hp + 32 + g*8);
        #pragma unroll
        for (int pt = 0; pt < 6; ++pt) {
            short8 B0 = WF[(PRJ_S + pt*2 + 0)*64 + l];
            short8 B1 = WF[(PRJ_S + pt*2 + 1)*64 + l];
            f32x4 p = (f32x4){bias[pt], bias[pt], bias[pt], bias[pt]};
            p = MFMA(ah0, B0, p);
            p = MFMA(ah1, B1, p);
            #pragma unroll
            for (int r = 0; r < 4; ++r) PLw[(4*g + r)*100 + pt*16 + c] = p[r];
        }
        asm volatile("s_waitcnt lgkmcnt(0)" ::: "memory");
        __builtin_amdgcn_sched_barrier(0);

        float2 tv = *reinterpret_cast<const float2*>(pred_seqs + b_s*1200 + t*24 + 20);
        float a[4], m = -1e30f, Ppi = 0.0f;
        #pragma unroll
        for (int i = 0; i < 4; ++i) {
            int cq = q4*4 + i;
            float pi = PLw[s*100 + cq];
            float2 mu = *reinterpret_cast<const float2*>(PLw + s*100 + 16 + 2*cq);
            float2 ls = *reinterpret_cast<const float2*>(PLw + s*100 + 48 + 2*cq);
            float co = PLw[s*100 + 80 + cq];
            float l0 = fminf(fmaxf(ls.x, -10.0f), 10.0f);
            float l1 = fminf(fmaxf(ls.y, -10.0f), 10.0f);
            float z0 = (tv.x - mu.x) * __expf(-l0);
            float z1 = (tv.y - mu.y) * __expf(-l1);
            float ct = tanh_(co);
            float omr = 1.0f - ct*ct;
            float quad = z0*z0 + z1*z1 - 2.0f*ct*z0*z1;
            float comp = -1.8378770664093453f - (l0 + l1) - 0.5f*__logf(omr) - 0.5f*quad/omr;
            a[i] = pi + comp;
            m = fmaxf(m, a[i]);
            Ppi += __expf(pi);
        }
        m = fmaxf(m, __shfl_xor(m, 1));
        m = fmaxf(m, __shfl_xor(m, 2));
        float E = __expf(a[0]-m) + __expf(a[1]-m) + __expf(a[2]-m) + __expf(a[3]-m);
        E   += __shfl_xor(E, 1);   E   += __shfl_xor(E, 2);
        Ppi += __shfl_xor(Ppi, 1); Ppi += __shfl_xor(Ppi, 2);
        float logp = m + __logf(E) - __logf(Ppi);
        sum_local += fminf(logp, 50.0f);
    }
    if (q4 == 0) atomicAdd(out + n_s, sum_local);
}

extern "C" void kernel_launch(void* const* d_in, const int* in_sizes, int n_in,
                              void* d_out, int out_size, void* d_ws, size_t ws_size,
                              hipStream_t stream) {
    const float* x     = (const float*)d_in[0];
    const float* z     = (const float*)d_in[1];
    const float* iseq  = (const float*)d_in[2];
    const float* pseq  = (const float*)d_in[3];
    const float* Wh0   = (const float*)d_in[4];
    const float* bh0   = (const float*)d_in[5];
    const float* Wc0   = (const float*)d_in[6];
    const float* bc0   = (const float*)d_in[7];
    const float* Wih   = (const float*)d_in[8];
    const float* Whh   = (const float*)d_in[9];
    const float* bih   = (const float*)d_in[10];
    const float* bhh   = (const float*)d_in[11];
    const float* Wpi   = (const float*)d_in[12];
    const float* bpi   = (const float*)d_in[13];
    const float* Wmu   = (const float*)d_in[14];
    const float* bmu   = (const float*)d_in[15];
    const float* Wls   = (const float*)d_in[16];
    const float* bls   = (const float*)d_in[17];
    const float* Wcorr = (const float*)d_in[18];
    const float* bcorr = (const float*)d_in[19];
    float* out = (float*)d_out;

    char* ws = (char*)d_ws;
    unsigned short* Hout = (unsigned short*)(ws + HOUT_B);
    short8* WF = (short8*)(ws + WF_B);

    pack_kernel<<<71, 256, 0, stream>>>(Wih, Whh, Wh0, Wc0, Wpi, Wmu, Wls, Wcorr, WF);
    hipMemsetAsync(d_out, 0, 4096 * sizeof(float), stream);
    lstm_kernel<<<512, 256, 0, stream>>>(x, z, iseq, pseq, Wih, bh0, bc0, bih, bhh,
                                         Hout, (const short8*)WF);
    head_kernel<<<1024, 256, 0, stream>>>(pseq, bpi, bmu, bls, bcorr,
                                          (const unsigned short*)Hout,
                                          (const short8*)WF, out);
}

// Round 12
// 102.983 us; speedup vs baseline: 1.4173x; 1.0097x over previous
//
#include <hip/hip_runtime.h>

// Decoder: N=4096 LSTM seqs (K=16 x B=256), H=64, T=50, GMM head (GC=16, PD=2).
// Round 12: R11 + phase-skew. Two co-resident blocks per CU run identical step
// lengths and phase-lock (R9 vs R11: +1 chain gave 0 gain at 47% VALUBusy).
// Odd blocks sleep ~2048 cyc before the loop -> half-step offset, stalls of one
// block fill the issue gaps of the other. Loop unrolled 2x (compile-time
// ping-pong). Everything else identical to R11.

#define T_ 50
typedef __attribute__((ext_vector_type(8))) short short8;
typedef __attribute__((ext_vector_type(4))) float f32x4;
#define MFMA(a,b,c) __builtin_amdgcn_mfma_f32_16x16x32_bf16(a,b,c,0,0,0)

// ws layout (bytes): Hout ushort[50][4096][64] = 26,214,400 ; WF after
#define HOUT_B 0u
#define WF_B   26214400u
#define WIH_S 0
#define WH0_S 320
#define WC0_S 400
#define WHH_S 480
#define PRJ_S 512

#define HFS 76   // h plane stride (ushorts)

__device__ __forceinline__ float sigf(float x)  { return 1.0f / (1.0f + __expf(-x)); }
__device__ __forceinline__ float tanh_(float x) { return 1.0f - 2.0f / (__expf(2.0f * x) + 1.0f); }

__device__ __forceinline__ void splitf(float f, unsigned short& hi, unsigned short& lo) {
    unsigned b = __float_as_uint(f);
    hi = (unsigned short)(b >> 16);
    float fh = __uint_as_float(b & 0xffff0000u);
    lo = (unsigned short)(__float_as_uint(f - fh) >> 16);
}
__device__ __forceinline__ void pack8(const float* p, short8& hi, short8& lo) {
    #pragma unroll
    for (int e = 0; e < 8; ++e) {
        unsigned short h, l;
        splitf(p[e], h, l);
        hi[e] = (short)h; lo[e] = (short)l;
    }
}
__device__ __forceinline__ unsigned short bf16rn(float f) {
    unsigned b = __float_as_uint(f);
    unsigned r = b + 0x7fffu + ((b >> 16) & 1u);
    return (unsigned short)(r >> 16);
}
__device__ __forceinline__ void pack8rn(const float* p, short8& hi) {
    #pragma unroll
    for (int e = 0; e < 8; ++e) hi[e] = (short)bf16rn(p[e]);
}

// ---------------- k0: weight packing ----------------
__global__ void pack_kernel(const float* __restrict__ Wih, const float* __restrict__ Whh,
                            const float* __restrict__ Wh0, const float* __restrict__ Wc0,
                            const float* __restrict__ Wpi, const float* __restrict__ Wmu,
                            const float* __restrict__ Wls, const float* __restrict__ Wcorr,
                            short8* __restrict__ WF)
{
    int id = blockIdx.x * 256 + threadIdx.x;
    if (id >= 18176) return;
    if (id < 10240) {                               // Wih hi/lo
        int ks = id >> 10, rem = id & 1023;
        int q = rem >> 8, w = (rem >> 6) & 3, l = rem & 63;
        int g = l >> 4, c = l & 15;
        const float* src = Wih + (q*64 + w*16 + c)*322 + ks*32 + g*8;
        short8 hi, lo; pack8(src, hi, lo);
        WF[(WIH_S + ((ks*4 + q)*2 + 0)*4 + w)*64 + l] = hi;
        WF[(WIH_S + ((ks*4 + q)*2 + 1)*4 + w)*64 + l] = lo;
    } else if (id < 12800) {                        // Wh0 hi/lo
        int t2 = id - 10240;
        int ks = t2 >> 8, w = (t2 >> 6) & 3, l = t2 & 63;
        int g = l >> 4, c = l & 15;
        const float* src = Wh0 + (w*16 + c)*320 + ks*32 + g*8;
        short8 hi, lo; pack8(src, hi, lo);
        WF[(WH0_S + (ks*2 + 0)*4 + w)*64 + l] = hi;
        WF[(WH0_S + (ks*2 + 1)*4 + w)*64 + l] = lo;
    } else if (id < 15360) {                        // Wc0 hi/lo
        int t2 = id - 12800;
        int ks = t2 >> 8, w = (t2 >> 6) & 3, l = t2 & 63;
        int g = l >> 4, c = l & 15;
        const float* src = Wc0 + (w*16 + c)*320 + ks*32 + g*8;
        short8 hi, lo; pack8(src, hi, lo);
        WF[(WC0_S + (ks*2 + 0)*4 + w)*64 + l] = hi;
        WF[(WC0_S + (ks*2 + 1)*4 + w)*64 + l] = lo;
    } else if (id < 17408) {                        // Whh RNE
        int t3 = id - 15360;
        int slot = t3 >> 6, l = t3 & 63;
        int g = l >> 4, c = l & 15;
        int tile = slot >> 1, ks = slot & 1;
        int q = tile >> 2, wt = tile & 3;
        short8 hi; pack8rn(Whh + (q*64 + 16*wt + c)*64 + ks*32 + g*8, hi);
        WF[(WHH_S + slot)*64 + l] = hi;
    } else {                                        // proj RNE (12 slots)
        int t4 = id - 17408;
        int r = t4 >> 6, l = t4 & 63;
        int g = l >> 4, c = l & 15;
        int pt = r >> 1, ks = r & 1;
        int r3 = pt*16 + c;
        const float* p;
        if      (r3 < 16) p = Wpi   + r3*64;
        else if (r3 < 48) p = Wmu   + (r3-16)*64;
        else if (r3 < 80) p = Wls   + (r3-48)*64;
        else              p = Wcorr + (r3-80)*64;
        short8 hi; pack8rn(p + ks*32 + g*8, hi);
        WF[(PRJ_S + r)*64 + l] = hi;
    }
}

// ---------------- k1: LSTM recurrence only ----------------
__launch_bounds__(256, 2)
__global__ void lstm_kernel(
    const float* __restrict__ x,        const float* __restrict__ z,
    const float* __restrict__ inp_seqs, const float* __restrict__ pred_seqs,
    const float* __restrict__ Wih,      const float* __restrict__ bh0,
    const float* __restrict__ bc0,      const float* __restrict__ bih,
    const float* __restrict__ bhh,
    unsigned short* __restrict__ Hout,  const short8* __restrict__ WF)
{
    __shared__ __align__(16) float ZXL[16*324];            // rows 2s filled
    __shared__ __align__(16) float DQ[T_*16];              // d inputs (8 samples x 2)
    __shared__ __align__(16) unsigned short HP[4][16*HFS]; // h0hi,h0lo,h1hi,h1lo

    const int j = threadIdx.x;
    const int w = j >> 6, l = j & 63, g = l >> 4, c = l & 15;
    const int U = 16*w + c;
    const int blk = blockIdx.x, nb = blk*8;

    // ---- zero ZXL + HP
    for (int e = j; e < 16*324; e += 256) ZXL[e] = 0.0f;
    for (int e = j; e < 4*16*HFS; e += 256) (&HP[0][0])[e] = 0;
    __syncthreads();
    // ---- fill ZXL even rows; DQ (t=0 present, else FUT[t-1])
    for (int e = j; e < 8*320; e += 256) {
        int s = e / 320, k = e - s*320;
        int n = nb + s, b = n & 255;
        ZXL[(2*s)*324 + k] = (k < 64) ? z[n*64 + k] : x[b*256 + (k - 64)];
    }
    for (int e = j; e < T_*16; e += 256) {
        int t = e >> 4, rem = e & 15, s = rem >> 1, comp = rem & 1;
        int b = (nb + s) & 255;
        DQ[e] = (t == 0) ? inp_seqs[b*192 + 188 + comp]
                         : pred_seqs[b*1200 + (t-1)*24 + 20 + comp];
    }
    __syncthreads();

    // ---- prologue GEMM: wave w -> 4 gc tiles (units 16w..16w+15), h0, c0
    f32x4 gcA[4], h0a, c0a;
    #pragma unroll
    for (int q = 0; q < 4; ++q) {
        int ga = q*64 + U;
        float b_ = bih[ga] + bhh[ga];
        gcA[q] = (f32x4){b_, 0.0f, b_, 0.0f};
    }
    {
        float bh_ = bh0[U], bc_ = bc0[U];
        h0a = (f32x4){bh_, 0.0f, bh_, 0.0f};
        c0a = (f32x4){bc_, 0.0f, bc_, 0.0f};
    }
    for (int ks = 0; ks < 10; ++ks) {
        short8 ah, al;
        pack8(&ZXL[c*324 + ks*32 + g*8], ah, al);
        #pragma unroll
        for (int q = 0; q < 4; ++q) {
            short8 Bh = WF[(WIH_S + ((ks*4 + q)*2 + 0)*4 + w)*64 + l];
            short8 Bl = WF[(WIH_S + ((ks*4 + q)*2 + 1)*4 + w)*64 + l];
            gcA[q] = MFMA(ah, Bh, gcA[q]);
            gcA[q] = MFMA(ah, Bl, gcA[q]);
            gcA[q] = MFMA(al, Bh, gcA[q]);
        }
        {
            short8 Bh = WF[(WH0_S + (ks*2 + 0)*4 + w)*64 + l];
            short8 Bl = WF[(WH0_S + (ks*2 + 1)*4 + w)*64 + l];
            h0a = MFMA(ah, Bh, h0a); h0a = MFMA(ah, Bl, h0a); h0a = MFMA(al, Bh, h0a);
        }
        {
            short8 Bh = WF[(WC0_S + (ks*2 + 0)*4 + w)*64 + l];
            short8 Bl = WF[(WC0_S + (ks*2 + 1)*4 + w)*64 + l];
            c0a = MFMA(ah, Bh, c0a); c0a = MFMA(ah, Bl, c0a); c0a = MFMA(al, Bh, c0a);
        }
    }
    // this lane's cell elements: D rows 4g (r=0) and 4g+2 (r=2)
    //   -> samples 2g, 2g+1 at unit U
    float gcs0[4], gcs1[4];
    #pragma unroll
    for (int q = 0; q < 4; ++q) { gcs0[q] = gcA[q][0]; gcs1[q] = gcA[q][2]; }
    float cst0 = c0a[0], cst1 = c0a[2];
    {
        unsigned short hh, ll;
        splitf(h0a[0], hh, ll);
        HP[0][(4*g)*HFS + U] = hh;     HP[1][(4*g)*HFS + U] = ll;
        splitf(h0a[2], hh, ll);
        HP[0][(4*g + 2)*HFS + U] = hh; HP[1][(4*g + 2)*HFS + U] = ll;
    }
    // d-weights + Whh RNE frags
    float wd0[4], wd1[4];
    #pragma unroll
    for (int q = 0; q < 4; ++q) {
        int ga = q*64 + U;
        wd0[q] = Wih[ga*322 + 320];
        wd1[q] = Wih[ga*322 + 321];
    }
    short8 WB[4][2];
    #pragma unroll
    for (int q = 0; q < 4; ++q)
        #pragma unroll
        for (int ks = 0; ks < 2; ++ks)
            WB[q][ks] = WF[(WHH_S + (q*4 + w)*2 + ks)*64 + l];

    asm volatile("s_waitcnt lgkmcnt(0)" ::: "memory");
    __builtin_amdgcn_s_barrier();
    asm volatile("" ::: "memory");

    // ---- phase skew: odd blocks offset by ~half a step so the two
    //      co-resident blocks' stall windows interleave instead of aligning.
    if (blk & 1) {
        __builtin_amdgcn_s_sleep(32);   // ~2048 cycles
    }

    // ---- main loop: raw barrier, lgkm-only waits, vmcnt never drained
    auto step = [&](int t,
                    const unsigned short* Hh, const unsigned short* Hl,
                    unsigned short* Nh, unsigned short* Nl) {
        short8 ah0 = *reinterpret_cast<const short8*>(Hh + c*HFS +      g*8);
        short8 al0 = *reinterpret_cast<const short8*>(Hl + c*HFS +      g*8);
        short8 ah1 = *reinterpret_cast<const short8*>(Hh + c*HFS + 32 + g*8);
        short8 al1 = *reinterpret_cast<const short8*>(Hl + c*HFS + 32 + g*8);
        f32x4 dv = *reinterpret_cast<const f32x4*>(DQ + t*16 + 4*g);  // dx0,dy0,dx1,dy1

        f32x4 aq[4];
        #pragma unroll
        for (int q = 0; q < 4; ++q) {
            f32x4 a;
            a[0] = gcs0[q] + dv[0]*wd0[q] + dv[1]*wd1[q];
            a[1] = 0.0f;
            a[2] = gcs1[q] + dv[2]*wd0[q] + dv[3]*wd1[q];
            a[3] = 0.0f;
            a = MFMA(ah0, WB[q][0], a);
            a = MFMA(al0, WB[q][0], a);
            a = MFMA(ah1, WB[q][1], a);
            a = MFMA(al1, WB[q][1], a);
            aq[q] = a;
        }
        float cc0 = sigf(aq[1][0])*cst0 + sigf(aq[0][0])*tanh_(aq[2][0]);
        float cc1 = sigf(aq[1][2])*cst1 + sigf(aq[0][2])*tanh_(aq[2][2]);
        cst0 = cc0; cst1 = cc1;
        float hv0 = sigf(aq[3][0])*tanh_(cc0);
        float hv1 = sigf(aq[3][2])*tanh_(cc1);
        unsigned short hh, ll;
        splitf(hv0, hh, ll);
        Nh[(4*g)*HFS + U] = hh;     Nl[(4*g)*HFS + U] = ll;
        splitf(hv1, hh, ll);
        Nh[(4*g + 2)*HFS + U] = hh; Nl[(4*g + 2)*HFS + U] = ll;
        Hout[(size_t)(t*4096 + nb + 2*g)*64 + U]     = bf16rn(hv0);
        Hout[(size_t)(t*4096 + nb + 2*g + 1)*64 + U] = bf16rn(hv1);

        asm volatile("s_waitcnt lgkmcnt(0)" ::: "memory");
        __builtin_amdgcn_s_barrier();
        asm volatile("" ::: "memory");
    };

    for (int tt = 0; tt < T_/2; ++tt) {
        step(2*tt,     HP[0], HP[1], HP[2], HP[3]);
        step(2*tt + 1, HP[2], HP[3], HP[0], HP[1]);
    }
}

// ---------------- k2: proj + GMM ----------------
__launch_bounds__(256, 3)
__global__ void head_kernel(const float* __restrict__ pred_seqs,
                            const float* __restrict__ bpi, const float* __restrict__ bmu,
                            const float* __restrict__ bls, const float* __restrict__ bcorr,
                            const unsigned short* __restrict__ Hin,
                            const short8* __restrict__ WF,
                            float* __restrict__ out)
{
    __shared__ __align__(16) float PL[4][1600];   // per-wave 16 x 100
    const int j = threadIdx.x;
    const int w = j >> 6;
    const int l = j & 63;
    const int g = l >> 4;
    const int c = l & 15;
    const int blk = blockIdx.x;
    const int set = blk >> 2, chunk = blk & 3;
    const int t0 = (chunk*25) >> 1, t1 = ((chunk+1)*25) >> 1;

    float bias[6];
    #pragma unroll
    for (int pt = 0; pt < 6; ++pt) {
        int r3 = pt*16 + c;
        bias[pt] = (r3 < 16) ? bpi[r3] : (r3 < 48) ? bmu[r3-16]
                 : (r3 < 80) ? bls[r3-48] : bcorr[r3-80];
    }

    const int s = l >> 2, q4 = l & 3;
    const int n_s = set*16 + s, b_s = n_s & 255;
    float* PLw = &PL[w][0];
    float sum_local = 0.0f;

    for (int t = t0 + w; t < t1; t += 4) {
        const unsigned short* hp = Hin + (size_t)(t*4096 + set*16 + c)*64;
        short8 ah0 = *reinterpret_cast<const short8*>(hp + g*8);
        short8 ah1 = *reinterpret_cast<const short8*>(hp + 32 + g*8);
        #pragma unroll
        for (int pt = 0; pt < 6; ++pt) {
            short8 B0 = WF[(PRJ_S + pt*2 + 0)*64 + l];
            short8 B1 = WF[(PRJ_S + pt*2 + 1)*64 + l];
            f32x4 p = (f32x4){bias[pt], bias[pt], bias[pt], bias[pt]};
            p = MFMA(ah0, B0, p);
            p = MFMA(ah1, B1, p);
            #pragma unroll
            for (int r = 0; r < 4; ++r) PLw[(4*g + r)*100 + pt*16 + c] = p[r];
        }
        asm volatile("s_waitcnt lgkmcnt(0)" ::: "memory");
        __builtin_amdgcn_sched_barrier(0);

        float2 tv = *reinterpret_cast<const float2*>(pred_seqs + b_s*1200 + t*24 + 20);
        float a[4], m = -1e30f, Ppi = 0.0f;
        #pragma unroll
        for (int i = 0; i < 4; ++i) {
            int cq = q4*4 + i;
            float pi = PLw[s*100 + cq];
            float2 mu = *reinterpret_cast<const float2*>(PLw + s*100 + 16 + 2*cq);
            float2 ls = *reinterpret_cast<const float2*>(PLw + s*100 + 48 + 2*cq);
            float co = PLw[s*100 + 80 + cq];
            float l0 = fminf(fmaxf(ls.x, -10.0f), 10.0f);
            float l1 = fminf(fmaxf(ls.y, -10.0f), 10.0f);
            float z0 = (tv.x - mu.x) * __expf(-l0);
            float z1 = (tv.y - mu.y) * __expf(-l1);
            float ct = tanh_(co);
            float omr = 1.0f - ct*ct;
            float quad = z0*z0 + z1*z1 - 2.0f*ct*z0*z1;
            float comp = -1.8378770664093453f - (l0 + l1) - 0.5f*__logf(omr) - 0.5f*quad/omr;
            a[i] = pi + comp;
            m = fmaxf(m, a[i]);
            Ppi += __expf(pi);
        }
        m = fmaxf(m, __shfl_xor(m, 1));
        m = fmaxf(m, __shfl_xor(m, 2));
        float E = __expf(a[0]-m) + __expf(a[1]-m) + __expf(a[2]-m) + __expf(a[3]-m);
        E   += __shfl_xor(E, 1);   E   += __shfl_xor(E, 2);
        Ppi += __shfl_xor(Ppi, 1); Ppi += __shfl_xor(Ppi, 2);
        float logp = m + __logf(E) - __logf(Ppi);
        sum_local += fminf(logp, 50.0f);
    }
    if (q4 == 0) atomicAdd(out + n_s, sum_local);
}

extern "C" void kernel_launch(void* const* d_in, const int* in_sizes, int n_in,
                              void* d_out, int out_size, void* d_ws, size_t ws_size,
                              hipStream_t stream) {
    const float* x     = (const float*)d_in[0];
    const float* z     = (const float*)d_in[1];
    const float* iseq  = (const float*)d_in[2];
    const float* pseq  = (const float*)d_in[3];
    const float* Wh0   = (const float*)d_in[4];
    const float* bh0   = (const float*)d_in[5];
    const float* Wc0   = (const float*)d_in[6];
    const float* bc0   = (const float*)d_in[7];
    const float* Wih   = (const float*)d_in[8];
    const float* Whh   = (const float*)d_in[9];
    const float* bih   = (const float*)d_in[10];
    const float* bhh   = (const float*)d_in[11];
    const float* Wpi   = (const float*)d_in[12];
    const float* bpi   = (const float*)d_in[13];
    const float* Wmu   = (const float*)d_in[14];
    const float* bmu   = (const float*)d_in[15];
    const float* Wls   = (const float*)d_in[16];
    const float* bls   = (const float*)d_in[17];
    const float* Wcorr = (const float*)d_in[18];
    const float* bcorr = (const float*)d_in[19];
    float* out = (float*)d_out;

    char* ws = (char*)d_ws;
    unsigned short* Hout = (unsigned short*)(ws + HOUT_B);
    short8* WF = (short8*)(ws + WF_B);

    pack_kernel<<<71, 256, 0, stream>>>(Wih, Whh, Wh0, Wc0, Wpi, Wmu, Wls, Wcorr, WF);
    hipMemsetAsync(d_out, 0, 4096 * sizeof(float), stream);
    lstm_kernel<<<512, 256, 0, stream>>>(x, z, iseq, pseq, Wih, bh0, bc0, bih, bhh,
                                         Hout, (const short8*)WF);
    head_kernel<<<1024, 256, 0, stream>>>(pseq, bpi, bmu, bls, bcorr,
                                          (const unsigned short*)Hout,
                                          (const short8*)WF, out);
}